// Round 18
// baseline (558.434 us; speedup 1.0000x reference)
//
#include <hip/hip_runtime.h>

typedef float f32x4 __attribute__((ext_vector_type(4)));

#define TSTEPS 500
#define BDIM 64
#define CIN 512
#define COUT 512
#define MTOT (TSTEPS * BDIM)   // 32000
#define NCH (BDIM * CIN)       // 32768
#define SNEUR (BDIM * COUT)    // 32768
#define OUTN ((size_t)TSTEPS * SNEUR + SNEUR)

#define AL64 0.95122942450071400909   // math.exp(-0.001/0.02), f64
#define BL64 (1.0 - AL64)

#define BUF_BYTES 65536000ull  // one [32000,512] f32 plane
#define WS_NEED (3ull * BUF_BYTES)

__global__ __launch_bounds__(256) void fill_const_f32(
    float* __restrict__ p, size_t n, float c) {
  size_t i = (size_t)blockIdx.x * 256 + threadIdx.x;
  const size_t stride = (size_t)gridDim.x * 256;
  for (; i < n; i += stride) p[i] = c;
}

// ---------------------------------------------------------------------------
// f32 trace scan (np-exact): tr = fl(fl(a*tr) + x)   [proven R13]
// ---------------------------------------------------------------------------
__global__ __launch_bounds__(256) void trace32(
    const float* __restrict__ X, float* __restrict__ TR,
    const float* __restrict__ alpha) {
  const int j = blockIdx.x * 256 + threadIdx.x;  // b*512 + ci
  const float a = fminf(fmaxf(alpha[0], 0.0f), 0.9999f);
  float tr = 0.0f;
#pragma unroll 10
  for (int t = 0; t < TSTEPS; ++t) {
    float x = X[(size_t)t * NCH + j];
    tr = __fadd_rn(__fmul_rn(a, tr), x);
    TR[(size_t)t * NCH + j] = tr;
  }
}

// ---------------------------------------------------------------------------
// Head/tail split GEMM, 128x128 tile, 8x8 per thread per chain (128 accs).
// Reduction order bit-identical to R13/R17 (proven): ascending-k f32 FMA
// chain per chain, split at k=384; combine fadd(fadd(xH,xT), fadd(tH,tT)).
// - A-tile LDS: [128][16] linear rows, k-group XOR-swizzled on the WRITE
//   (col g^((row>>3)&3)); read G = kg^(ty&3) -> 4 distinct bank quads,
//   conflict-free reads.
// - Register prefetch of next tile's 6 global f32x4 (latency under compute).
// - XCD-chunked block swizzle (1000 = 8 x 125), bn fastest -> L2 A reuse.
// PHASE 0: head (kt 0..24), writes PHx/PHt partials.
// PHASE 1: tail (kt 24..32), combines, writes CUR in-place over PHx.
// ---------------------------------------------------------------------------
template <int PHASE>
__global__ __launch_bounds__(256) void gemm8(
    const float* __restrict__ X, const float* __restrict__ TR,
    const float* __restrict__ W, float* __restrict__ PHx,
    float* __restrict__ PHt) {
  __shared__ __align__(16) float Asx[2048];  // [128 rows][16 k], swizzled
  __shared__ __align__(16) float Ast[2048];
  __shared__ __align__(16) float Bs[2048];   // [16 k][128 n], linear
  const int tid = threadIdx.x;
  const int ty = tid >> 4, tx = tid & 15;  // out: rows ty*8.., cols tx*4 / +64

  const int fid = blockIdx.x;
  const int swz = (fid & 7) * 125 + (fid >> 3);
  const int bm = (swz >> 2) * 128;  // 250 row-panels
  const int bn = (swz & 3) * 128;   // 4 col-panels (fastest -> same XCD)

  // staging: A = 128 rows x 2 halves (8 floats each); B = 16 rows x 8 floats
  const int arow = tid >> 1, ahalf = tid & 1;
  const int asw = (arow >> 3) & 3;
  const int aw0 = (((ahalf * 2) ^ asw)) * 4;      // swizzled LDS col offsets
  const int aw1 = (((ahalf * 2 + 1) ^ asw)) * 4;
  const int brow = tid >> 4, bcol = (tid & 15) * 8;

  const int KT0 = PHASE ? 24 : 0;
  const int KT1 = PHASE ? 32 : 24;

  const float* gx = X + (size_t)(bm + arow) * CIN + KT0 * 16 + ahalf * 8;
  const float* gt = TR + (size_t)(bm + arow) * CIN + KT0 * 16 + ahalf * 8;
  const float* gw = W + (size_t)(KT0 * 16 + brow) * COUT + bn + bcol;

  float xA[8][8] = {{0.0f}}, tA[8][8] = {{0.0f}};

  f32x4 rx0 = *(const f32x4*)gx, rx1 = *(const f32x4*)(gx + 4);
  f32x4 rt0 = *(const f32x4*)gt, rt1 = *(const f32x4*)(gt + 4);
  f32x4 rw0 = *(const f32x4*)gw, rw1 = *(const f32x4*)(gw + 4);

  for (int kt = KT0; kt < KT1; ++kt) {
    __syncthreads();  // previous compute done -> LDS reusable
    *(f32x4*)&Asx[arow * 16 + aw0] = rx0;
    *(f32x4*)&Asx[arow * 16 + aw1] = rx1;
    *(f32x4*)&Ast[arow * 16 + aw0] = rt0;
    *(f32x4*)&Ast[arow * 16 + aw1] = rt1;
    *(f32x4*)&Bs[brow * 128 + bcol] = rw0;
    *(f32x4*)&Bs[brow * 128 + bcol + 4] = rw1;
    __syncthreads();  // tile ready
    if (kt + 1 < KT1) {  // prefetch next tile; consumed at next ds_write
      gx += 16; gt += 16; gw += 16 * COUT;
      rx0 = *(const f32x4*)gx; rx1 = *(const f32x4*)(gx + 4);
      rt0 = *(const f32x4*)gt; rt1 = *(const f32x4*)(gt + 4);
      rw0 = *(const f32x4*)gw; rw1 = *(const f32x4*)(gw + 4);
    }
#pragma unroll
    for (int kg = 0; kg < 4; ++kg) {
      const int G = (kg ^ (ty & 3)) * 4;  // un-swizzle ((row>>3)&3 == ty&3)
      f32x4 ax[8], at8[8];
#pragma unroll
      for (int i = 0; i < 8; ++i) {
        ax[i] = *(const f32x4*)&Asx[(ty * 8 + i) * 16 + G];
        at8[i] = *(const f32x4*)&Ast[(ty * 8 + i) * 16 + G];
      }
#pragma unroll
      for (int k2 = 0; k2 < 4; ++k2) {
        f32x4 bL = *(const f32x4*)&Bs[(kg * 4 + k2) * 128 + tx * 4];
        f32x4 bH = *(const f32x4*)&Bs[(kg * 4 + k2) * 128 + 64 + tx * 4];
#pragma unroll
        for (int i = 0; i < 8; ++i)
#pragma unroll
          for (int j = 0; j < 4; ++j) {
            xA[i][j]     = fmaf(ax[i][k2], bL[j], xA[i][j]);
            xA[i][4 + j] = fmaf(ax[i][k2], bH[j], xA[i][4 + j]);
            tA[i][j]     = fmaf(at8[i][k2], bL[j], tA[i][j]);
            tA[i][4 + j] = fmaf(at8[i][k2], bH[j], tA[i][4 + j]);
          }
      }
    }
  }

#pragma unroll
  for (int i = 0; i < 8; ++i) {
    const size_t row = (size_t)(bm + ty * 8 + i);
    const size_t iL = row * COUT + bn + tx * 4;
    const size_t iH = row * COUT + bn + 64 + tx * 4;
    f32x4 xL, xH2, tL, tH2;
#pragma unroll
    for (int j = 0; j < 4; ++j) {
      xL[j] = xA[i][j];  xH2[j] = xA[i][4 + j];
      tL[j] = tA[i][j];  tH2[j] = tA[i][4 + j];
    }
    if (PHASE == 0) {
      *(f32x4*)&PHx[iL] = xL;   *(f32x4*)&PHx[iH] = xH2;
      *(f32x4*)&PHt[iL] = tL;   *(f32x4*)&PHt[iH] = tH2;
    } else {
      f32x4 hxL = *(const f32x4*)&PHx[iL];
      f32x4 hxH = *(const f32x4*)&PHx[iH];
      f32x4 htL = *(const f32x4*)&PHt[iL];
      f32x4 htH = *(const f32x4*)&PHt[iH];
      f32x4 oL, oH;
#pragma unroll
      for (int j = 0; j < 4; ++j) {
        // cur = fadd(fadd(xH,xT), fadd(tH,tT))  — proven combine order
        oL[j] = __fadd_rn(__fadd_rn(hxL[j], xL[j]), __fadd_rn(htL[j], tL[j]));
        oH[j] = __fadd_rn(__fadd_rn(hxH[j], xH2[j]), __fadd_rn(htH[j], tH2[j]));
      }
      *(f32x4*)&PHx[iL] = oL;  // in-place: PHx becomes CUR
      *(f32x4*)&PHx[iH] = oH;
    }
  }
}

// ---------------------------------------------------------------------------
// f32 LIF chain (np-exact): v = fl(fl(AL*v)+fl(BL*cur)); s=(v-1>0); reset.
// spikes {0,1}; rates = count/500.   [proven R13]
// ---------------------------------------------------------------------------
__global__ __launch_bounds__(256) void lif32(
    const float* __restrict__ CUR, float* __restrict__ spikes,
    float* __restrict__ rates) {
  const int j = blockIdx.x * 256 + threadIdx.x;  // b*512 + n
  const float AL = (float)AL64, BL = (float)BL64;
  float v = 0.0f;
  int cnt = 0;
#pragma unroll 10
  for (int t = 0; t < TSTEPS; ++t) {
    float cur = CUR[(size_t)t * SNEUR + j];
    v = __fadd_rn(__fmul_rn(AL, v), __fmul_rn(BL, cur));
    int sp = __fadd_rn(v, -1.0f) > 0.0f;
    cnt += sp;
    spikes[(size_t)t * SNEUR + j] = sp ? 1.0f : 0.0f;
    v = sp ? 0.0f : v;
  }
  rates[j] = __fdiv_rn((float)cnt, 500.0f);
}

extern "C" void kernel_launch(void* const* d_in, const int* in_sizes, int n_in,
                              void* d_out, int out_size, void* d_ws, size_t ws_size,
                              hipStream_t stream) {
  float* out = (float*)d_out;  // f32: spikes [500*64*512] ++ rates [64*512]

  float flag = 0.0f;
  const float* X = nullptr;
  const float* W = nullptr;
  const float* AP = nullptr;
  if (n_in != 3) {
    flag = 11.0f;
  } else {
    for (int i = 0; i < 3; ++i) {
      if (in_sizes[i] == 16384000) X = (const float*)d_in[i];
      else if (in_sizes[i] == 262144) W = (const float*)d_in[i];
      else if (in_sizes[i] == 1) AP = (const float*)d_in[i];
    }
    if (!X || !W || !AP) flag = 13.0f;
    else if (out_size != (int)OUTN) flag = 17.0f;
    else if (ws_size < WS_NEED) flag = 23.0f;
  }
  if (flag != 0.0f) {
    fill_const_f32<<<dim3(2048), dim3(256), 0, stream>>>(out, OUTN, flag);
    return;
  }

  char* ws = (char*)d_ws;
  float* TR = (float*)(ws);                    // trace    [32000,512] f32
  float* PHx = (float*)(ws + BUF_BYTES);       // x-head -> CUR (in-place)
  float* PHt = (float*)(ws + 2 * BUF_BYTES);   // trace-head partial

  trace32<<<dim3(NCH / 256), dim3(256), 0, stream>>>(X, TR, AP);
  gemm8<0><<<dim3(1000), dim3(256), 0, stream>>>(X, TR, W, PHx, PHt);
  gemm8<1><<<dim3(1000), dim3(256), 0, stream>>>(X, TR, W, PHx, PHt);
  lif32<<<dim3(SNEUR / 256), dim3(256), 0, stream>>>(
      PHx, out, out + (size_t)TSTEPS * SNEUR);
}

// Round 19
// 505.674 us; speedup vs baseline: 1.1043x; 1.1043x over previous
//
#include <hip/hip_runtime.h>

typedef float f32x4 __attribute__((ext_vector_type(4)));

#define TSTEPS 500
#define BDIM 64
#define CIN 512
#define COUT 512
#define MTOT (TSTEPS * BDIM)   // 32000
#define NCH (BDIM * CIN)       // 32768
#define SNEUR (BDIM * COUT)    // 32768
#define OUTN ((size_t)TSTEPS * SNEUR + SNEUR)

#define AL64 0.95122942450071400909   // math.exp(-0.001/0.02), f64
#define BL64 (1.0 - AL64)

#define BUF_BYTES 65536000ull  // one [32000,512] f32 plane
#define WS_NEED (3ull * BUF_BYTES)

__global__ __launch_bounds__(256) void fill_const_f32(
    float* __restrict__ p, size_t n, float c) {
  size_t i = (size_t)blockIdx.x * 256 + threadIdx.x;
  const size_t stride = (size_t)gridDim.x * 256;
  for (; i < n; i += stride) p[i] = c;
}

// ---------------------------------------------------------------------------
// f32 trace scan (np-exact): tr = fl(fl(a*tr) + x)   [proven R13]
// ---------------------------------------------------------------------------
__global__ __launch_bounds__(256) void trace32(
    const float* __restrict__ X, float* __restrict__ TR,
    const float* __restrict__ alpha) {
  const int j = blockIdx.x * 256 + threadIdx.x;  // b*512 + ci
  const float a = fminf(fmaxf(alpha[0], 0.0f), 0.9999f);
  float tr = 0.0f;
#pragma unroll 10
  for (int t = 0; t < TSTEPS; ++t) {
    float x = X[(size_t)t * NCH + j];
    tr = __fadd_rn(__fmul_rn(a, tr), x);
    TR[(size_t)t * NCH + j] = tr;
  }
}

// ---------------------------------------------------------------------------
// Head/tail split GEMM (R17 structure, proven 502us) + 2 fixes:
//  1. register prefetch of next tile (hides global latency under compute)
//  2. B ds_write loader bc=(tid&15)*4 at [bk][bc] & [bk][64+bc]
//     -> 16 lanes cover all 32 banks at 2/bank (free) vs old stride-8 4-way
// Geometry: BM=64 x BN=128, 256 thr, 4x8/thread, 2 chain-sets (64 accs).
// Reduction order bit-identical to R13/R17: ascending-k f32 FMA chain per
// chain, split at k=384 (BLAS KC); combine fadd(fadd(xH,xT), fadd(tH,tT)).
// XCD-chunked block swizzle (2000 = 8 x 250), bn fastest -> L2 A reuse.
// PHASE 0: head (kt 0..24) -> PHx/PHt partials.
// PHASE 1: tail (kt 24..32), combine, CUR in-place over PHx.
// ---------------------------------------------------------------------------
template <int PHASE>
__global__ __launch_bounds__(256) void gemmHT(
    const float* __restrict__ X, const float* __restrict__ TR,
    const float* __restrict__ W, float* __restrict__ PHx,
    float* __restrict__ PHt) {
  __shared__ __align__(16) float Asx[64][20];  // padded: row starts spread banks
  __shared__ __align__(16) float Ast[64][20];
  __shared__ __align__(16) float Bs[16][132];
  const int tid = threadIdx.x;
  const int ty = tid >> 4, tx = tid & 15;

  const int fid = blockIdx.x;
  const int swz = (fid & 7) * 250 + (fid >> 3);
  const int bm = (swz >> 2) * 64;   // 500 row-panels
  const int bn = (swz & 3) * 128;   // 4 col-panels (fastest -> same XCD)

  const int ar = tid >> 2, ak = (tid & 3) * 4;   // A loader: 64 rows x 16 k
  const int bk = tid >> 4, bc = (tid & 15) * 4;  // B loader: 16 k x (2x64) n

  const int KT0 = PHASE ? 24 : 0;
  const int KT1 = PHASE ? 32 : 24;

  const float* gx = X + (size_t)(bm + ar) * CIN + KT0 * 16 + ak;
  const float* gt = TR + (size_t)(bm + ar) * CIN + KT0 * 16 + ak;
  const float* gw0 = W + (size_t)(KT0 * 16 + bk) * COUT + bn + bc;
  const float* gw1 = W + (size_t)(KT0 * 16 + bk) * COUT + bn + 64 + bc;

  float xA[4][8] = {{0.0f}}, tA[4][8] = {{0.0f}};

  // prime the prefetch registers with tile KT0
  f32x4 rx = *(const f32x4*)gx;
  f32x4 rt = *(const f32x4*)gt;
  f32x4 rw0 = *(const f32x4*)gw0;
  f32x4 rw1 = *(const f32x4*)gw1;

  for (int kt = KT0; kt < KT1; ++kt) {
    __syncthreads();  // previous compute done -> LDS reusable
    *(f32x4*)&Asx[ar][ak] = rx;
    *(f32x4*)&Ast[ar][ak] = rt;
    *(f32x4*)&Bs[bk][bc] = rw0;
    *(f32x4*)&Bs[bk][64 + bc] = rw1;
    __syncthreads();  // tile ready
    if (kt + 1 < KT1) {  // prefetch next tile; latency hides under compute
      gx += 16; gt += 16; gw0 += 16 * COUT; gw1 += 16 * COUT;
      rx = *(const f32x4*)gx;
      rt = *(const f32x4*)gt;
      rw0 = *(const f32x4*)gw0;
      rw1 = *(const f32x4*)gw1;
    }
#pragma unroll
    for (int kg = 0; kg < 4; ++kg) {
      f32x4 ax[4], at4[4];
#pragma unroll
      for (int i = 0; i < 4; ++i) {
        ax[i] = *(const f32x4*)&Asx[ty * 4 + i][kg * 4];
        at4[i] = *(const f32x4*)&Ast[ty * 4 + i][kg * 4];
      }
#pragma unroll
      for (int k2 = 0; k2 < 4; ++k2) {
        f32x4 bL = *(const f32x4*)&Bs[kg * 4 + k2][tx * 4];
        f32x4 bH = *(const f32x4*)&Bs[kg * 4 + k2][64 + tx * 4];
#pragma unroll
        for (int i = 0; i < 4; ++i)
#pragma unroll
          for (int j = 0; j < 4; ++j) {
            xA[i][j]     = fmaf(ax[i][k2], bL[j], xA[i][j]);
            xA[i][4 + j] = fmaf(ax[i][k2], bH[j], xA[i][4 + j]);
            tA[i][j]     = fmaf(at4[i][k2], bL[j], tA[i][j]);
            tA[i][4 + j] = fmaf(at4[i][k2], bH[j], tA[i][4 + j]);
          }
      }
    }
  }

#pragma unroll
  for (int i = 0; i < 4; ++i) {
    const size_t row = (size_t)(bm + ty * 4 + i);
    const size_t iL = row * COUT + bn + tx * 4;
    const size_t iH = row * COUT + bn + 64 + tx * 4;
    f32x4 xL, xH2, tL, tH2;
#pragma unroll
    for (int j = 0; j < 4; ++j) {
      xL[j] = xA[i][j];  xH2[j] = xA[i][4 + j];
      tL[j] = tA[i][j];  tH2[j] = tA[i][4 + j];
    }
    if (PHASE == 0) {
      *(f32x4*)&PHx[iL] = xL;   *(f32x4*)&PHx[iH] = xH2;
      *(f32x4*)&PHt[iL] = tL;   *(f32x4*)&PHt[iH] = tH2;
    } else {
      f32x4 hxL = *(const f32x4*)&PHx[iL];
      f32x4 hxH = *(const f32x4*)&PHx[iH];
      f32x4 htL = *(const f32x4*)&PHt[iL];
      f32x4 htH = *(const f32x4*)&PHt[iH];
      f32x4 oL, oH;
#pragma unroll
      for (int j = 0; j < 4; ++j) {
        // cur = fadd(fadd(xH,xT), fadd(tH,tT))  — proven combine order
        oL[j] = __fadd_rn(__fadd_rn(hxL[j], xL[j]), __fadd_rn(htL[j], tL[j]));
        oH[j] = __fadd_rn(__fadd_rn(hxH[j], xH2[j]), __fadd_rn(htH[j], tH2[j]));
      }
      *(f32x4*)&PHx[iL] = oL;  // in-place: PHx becomes CUR
      *(f32x4*)&PHx[iH] = oH;
    }
  }
}

// ---------------------------------------------------------------------------
// f32 LIF chain (np-exact): v = fl(fl(AL*v)+fl(BL*cur)); s=(v-1>0); reset.
// spikes {0,1}; rates = count/500.   [proven R13]
// ---------------------------------------------------------------------------
__global__ __launch_bounds__(256) void lif32(
    const float* __restrict__ CUR, float* __restrict__ spikes,
    float* __restrict__ rates) {
  const int j = blockIdx.x * 256 + threadIdx.x;  // b*512 + n
  const float AL = (float)AL64, BL = (float)BL64;
  float v = 0.0f;
  int cnt = 0;
#pragma unroll 10
  for (int t = 0; t < TSTEPS; ++t) {
    float cur = CUR[(size_t)t * SNEUR + j];
    v = __fadd_rn(__fmul_rn(AL, v), __fmul_rn(BL, cur));
    int sp = __fadd_rn(v, -1.0f) > 0.0f;
    cnt += sp;
    spikes[(size_t)t * SNEUR + j] = sp ? 1.0f : 0.0f;
    v = sp ? 0.0f : v;
  }
  rates[j] = __fdiv_rn((float)cnt, 500.0f);
}

extern "C" void kernel_launch(void* const* d_in, const int* in_sizes, int n_in,
                              void* d_out, int out_size, void* d_ws, size_t ws_size,
                              hipStream_t stream) {
  float* out = (float*)d_out;  // f32: spikes [500*64*512] ++ rates [64*512]

  float flag = 0.0f;
  const float* X = nullptr;
  const float* W = nullptr;
  const float* AP = nullptr;
  if (n_in != 3) {
    flag = 11.0f;
  } else {
    for (int i = 0; i < 3; ++i) {
      if (in_sizes[i] == 16384000) X = (const float*)d_in[i];
      else if (in_sizes[i] == 262144) W = (const float*)d_in[i];
      else if (in_sizes[i] == 1) AP = (const float*)d_in[i];
    }
    if (!X || !W || !AP) flag = 13.0f;
    else if (out_size != (int)OUTN) flag = 17.0f;
    else if (ws_size < WS_NEED) flag = 23.0f;
  }
  if (flag != 0.0f) {
    fill_const_f32<<<dim3(2048), dim3(256), 0, stream>>>(out, OUTN, flag);
    return;
  }

  char* ws = (char*)d_ws;
  float* TR = (float*)(ws);                    // trace    [32000,512] f32
  float* PHx = (float*)(ws + BUF_BYTES);       // x-head -> CUR (in-place)
  float* PHt = (float*)(ws + 2 * BUF_BYTES);   // trace-head partial

  trace32<<<dim3(NCH / 256), dim3(256), 0, stream>>>(X, TR, AP);
  gemmHT<0><<<dim3(2000), dim3(256), 0, stream>>>(X, TR, W, PHx, PHt);
  gemmHT<1><<<dim3(2000), dim3(256), 0, stream>>>(X, TR, W, PHx, PHt);
  lif32<<<dim3(SNEUR / 256), dim3(256), 0, stream>>>(
      PHx, out, out + (size_t)TSTEPS * SNEUR);
}

// Round 20
// 499.743 us; speedup vs baseline: 1.1174x; 1.0119x over previous
//
#include <hip/hip_runtime.h>

typedef float f32x4 __attribute__((ext_vector_type(4)));

#define TSTEPS 500
#define BDIM 64
#define CIN 512
#define COUT 512
#define MTOT (TSTEPS * BDIM)   // 32000
#define NCH (BDIM * CIN)       // 32768
#define SNEUR (BDIM * COUT)    // 32768
#define OUTN ((size_t)TSTEPS * SNEUR + SNEUR)

#define AL64 0.95122942450071400909   // math.exp(-0.001/0.02), f64
#define BL64 (1.0 - AL64)

#define BUF_BYTES 65536000ull  // one [32000,512] f32 plane
#define WS_NEED (3ull * BUF_BYTES)

__global__ __launch_bounds__(256) void fill_const_f32(
    float* __restrict__ p, size_t n, float c) {
  size_t i = (size_t)blockIdx.x * 256 + threadIdx.x;
  const size_t stride = (size_t)gridDim.x * 256;
  for (; i < n; i += stride) p[i] = c;
}

// ---------------------------------------------------------------------------
// f32 trace scan (np-exact): tr = fl(fl(a*tr) + x)   [proven R13]
// ---------------------------------------------------------------------------
__global__ __launch_bounds__(256) void trace32(
    const float* __restrict__ X, float* __restrict__ TR,
    const float* __restrict__ alpha) {
  const int j = blockIdx.x * 256 + threadIdx.x;  // b*512 + ci
  const float a = fminf(fmaxf(alpha[0], 0.0f), 0.9999f);
  float tr = 0.0f;
#pragma unroll 10
  for (int t = 0; t < TSTEPS; ++t) {
    float x = X[(size_t)t * NCH + j];
    tr = __fadd_rn(__fmul_rn(a, tr), x);
    TR[(size_t)t * NCH + j] = tr;
  }
}

// ---------------------------------------------------------------------------
// Head/tail split GEMM, BK=32 (R17/R19 structure with HALF the barriers per
// FMA — the saturating ~69% duty across R13..R19 matches barrier-drain cost,
// not LDS bandwidth). Geometry: BM=64 x BN=128, 256 thr, 4x8/thread,
// 2 chain-sets (64 accs), linear padded LDS, no prefetch (R19: dead weight).
// Reduction order bit-identical to R13..R19: k = kt*32 + kg*4 + k2 strictly
// ascending per chain; split at k=384 (BLAS KC); combine
// fadd(fadd(xH,xT), fadd(tH,tT)). XCD-chunked swizzle (2000 = 8 x 250).
// PHASE 0: head (tiles 0..12) -> PHx/PHt partials.
// PHASE 1: tail (tiles 12..16), combine, CUR in-place over PHx.
// ---------------------------------------------------------------------------
template <int PHASE>
__global__ __launch_bounds__(256) void gemmK32(
    const float* __restrict__ X, const float* __restrict__ TR,
    const float* __restrict__ W, float* __restrict__ PHx,
    float* __restrict__ PHt) {
  __shared__ __align__(16) float Asx[64][36];  // 64 rows x 32 k, padded
  __shared__ __align__(16) float Ast[64][36];
  __shared__ __align__(16) float Bs[32][132];  // 32 k x 128 n, padded
  const int tid = threadIdx.x;
  const int ty = tid >> 4, tx = tid & 15;

  const int fid = blockIdx.x;
  const int swz = (fid & 7) * 250 + (fid >> 3);
  const int bm = (swz >> 2) * 64;   // 500 row-panels
  const int bn = (swz & 3) * 128;   // 4 col-panels (fastest -> same XCD)

  const int ar = tid >> 2, akb = (tid & 3) * 8;  // A loader: 64 rows x 32 k
  const int bk = tid >> 3, bc4 = (tid & 7) * 4;  // B loader: 32 k x 128 n

  const int KT0 = PHASE ? 12 : 0;
  const int KT1 = PHASE ? 16 : 12;

  const float* gx = X + (size_t)(bm + ar) * CIN + KT0 * 32 + akb;
  const float* gt = TR + (size_t)(bm + ar) * CIN + KT0 * 32 + akb;
  const float* gw = W + (size_t)(KT0 * 32 + bk) * COUT + bn + bc4;

  float xA[4][8] = {{0.0f}}, tA[4][8] = {{0.0f}};

  for (int kt = KT0; kt < KT1; ++kt) {
    __syncthreads();  // previous compute done -> LDS reusable
    *(f32x4*)&Asx[ar][akb]     = *(const f32x4*)gx;
    *(f32x4*)&Asx[ar][akb + 4] = *(const f32x4*)(gx + 4);
    *(f32x4*)&Ast[ar][akb]     = *(const f32x4*)gt;
    *(f32x4*)&Ast[ar][akb + 4] = *(const f32x4*)(gt + 4);
#pragma unroll
    for (int q = 0; q < 4; ++q)
      *(f32x4*)&Bs[bk][bc4 + q * 32] = *(const f32x4*)(gw + q * 32);
    __syncthreads();  // tile ready
    gx += 32; gt += 32; gw += 32 * COUT;
#pragma unroll
    for (int kg = 0; kg < 8; ++kg) {
      f32x4 ax[4], at4[4];
#pragma unroll
      for (int i = 0; i < 4; ++i) {
        ax[i] = *(const f32x4*)&Asx[ty * 4 + i][kg * 4];
        at4[i] = *(const f32x4*)&Ast[ty * 4 + i][kg * 4];
      }
#pragma unroll
      for (int k2 = 0; k2 < 4; ++k2) {
        f32x4 bL = *(const f32x4*)&Bs[kg * 4 + k2][tx * 4];
        f32x4 bH = *(const f32x4*)&Bs[kg * 4 + k2][64 + tx * 4];
#pragma unroll
        for (int i = 0; i < 4; ++i)
#pragma unroll
          for (int j = 0; j < 4; ++j) {
            xA[i][j]     = fmaf(ax[i][k2], bL[j], xA[i][j]);
            xA[i][4 + j] = fmaf(ax[i][k2], bH[j], xA[i][4 + j]);
            tA[i][j]     = fmaf(at4[i][k2], bL[j], tA[i][j]);
            tA[i][4 + j] = fmaf(at4[i][k2], bH[j], tA[i][4 + j]);
          }
      }
    }
  }

#pragma unroll
  for (int i = 0; i < 4; ++i) {
    const size_t row = (size_t)(bm + ty * 4 + i);
    const size_t iL = row * COUT + bn + tx * 4;
    const size_t iH = row * COUT + bn + 64 + tx * 4;
    f32x4 xL, xH2, tL, tH2;
#pragma unroll
    for (int j = 0; j < 4; ++j) {
      xL[j] = xA[i][j];  xH2[j] = xA[i][4 + j];
      tL[j] = tA[i][j];  tH2[j] = tA[i][4 + j];
    }
    if (PHASE == 0) {
      *(f32x4*)&PHx[iL] = xL;   *(f32x4*)&PHx[iH] = xH2;
      *(f32x4*)&PHt[iL] = tL;   *(f32x4*)&PHt[iH] = tH2;
    } else {
      f32x4 hxL = *(const f32x4*)&PHx[iL];
      f32x4 hxH = *(const f32x4*)&PHx[iH];
      f32x4 htL = *(const f32x4*)&PHt[iL];
      f32x4 htH = *(const f32x4*)&PHt[iH];
      f32x4 oL, oH;
#pragma unroll
      for (int j = 0; j < 4; ++j) {
        // cur = fadd(fadd(xH,xT), fadd(tH,tT))  — proven combine order
        oL[j] = __fadd_rn(__fadd_rn(hxL[j], xL[j]), __fadd_rn(htL[j], tL[j]));
        oH[j] = __fadd_rn(__fadd_rn(hxH[j], xH2[j]), __fadd_rn(htH[j], tH2[j]));
      }
      *(f32x4*)&PHx[iL] = oL;  // in-place: PHx becomes CUR
      *(f32x4*)&PHx[iH] = oH;
    }
  }
}

// ---------------------------------------------------------------------------
// f32 LIF chain (np-exact): v = fl(fl(AL*v)+fl(BL*cur)); s=(v-1>0); reset.
// spikes {0,1}; rates = count/500.   [proven R13]
// ---------------------------------------------------------------------------
__global__ __launch_bounds__(256) void lif32(
    const float* __restrict__ CUR, float* __restrict__ spikes,
    float* __restrict__ rates) {
  const int j = blockIdx.x * 256 + threadIdx.x;  // b*512 + n
  const float AL = (float)AL64, BL = (float)BL64;
  float v = 0.0f;
  int cnt = 0;
#pragma unroll 10
  for (int t = 0; t < TSTEPS; ++t) {
    float cur = CUR[(size_t)t * SNEUR + j];
    v = __fadd_rn(__fmul_rn(AL, v), __fmul_rn(BL, cur));
    int sp = __fadd_rn(v, -1.0f) > 0.0f;
    cnt += sp;
    spikes[(size_t)t * SNEUR + j] = sp ? 1.0f : 0.0f;
    v = sp ? 0.0f : v;
  }
  rates[j] = __fdiv_rn((float)cnt, 500.0f);
}

extern "C" void kernel_launch(void* const* d_in, const int* in_sizes, int n_in,
                              void* d_out, int out_size, void* d_ws, size_t ws_size,
                              hipStream_t stream) {
  float* out = (float*)d_out;  // f32: spikes [500*64*512] ++ rates [64*512]

  float flag = 0.0f;
  const float* X = nullptr;
  const float* W = nullptr;
  const float* AP = nullptr;
  if (n_in != 3) {
    flag = 11.0f;
  } else {
    for (int i = 0; i < 3; ++i) {
      if (in_sizes[i] == 16384000) X = (const float*)d_in[i];
      else if (in_sizes[i] == 262144) W = (const float*)d_in[i];
      else if (in_sizes[i] == 1) AP = (const float*)d_in[i];
    }
    if (!X || !W || !AP) flag = 13.0f;
    else if (out_size != (int)OUTN) flag = 17.0f;
    else if (ws_size < WS_NEED) flag = 23.0f;
  }
  if (flag != 0.0f) {
    fill_const_f32<<<dim3(2048), dim3(256), 0, stream>>>(out, OUTN, flag);
    return;
  }

  char* ws = (char*)d_ws;
  float* TR = (float*)(ws);                    // trace    [32000,512] f32
  float* PHx = (float*)(ws + BUF_BYTES);       // x-head -> CUR (in-place)
  float* PHt = (float*)(ws + 2 * BUF_BYTES);   // trace-head partial

  trace32<<<dim3(NCH / 256), dim3(256), 0, stream>>>(X, TR, AP);
  gemmK32<0><<<dim3(2000), dim3(256), 0, stream>>>(X, TR, W, PHx, PHt);
  gemmK32<1><<<dim3(2000), dim3(256), 0, stream>>>(X, TR, W, PHx, PHt);
  lif32<<<dim3(SNEUR / 256), dim3(256), 0, stream>>>(
      PHx, out, out + (size_t)TSTEPS * SNEUR);
}